// Round 2
// baseline (111.433 us; speedup 1.0000x reference)
//
#include <hip/hip_runtime.h>
#include <math.h>

#define NN 1024
#define IN_F 256
#define OUT_F 128
#define NHEADS 4
#define NHF 32
#define HPSTR 260  // LDS h-tile row stride in dwords: 256+4. 260%32==4 -> every
                   // ds_read_b128 across 64 lanes lands exactly 8 dwords/bank (the
                   // b128 floor) -> no bank-conflict penalty.

// K1: g_l = h @ Wl^T, g_r = h @ Wr^T -> [head][row][f] fp32.
// Grid 256 = 16 row-groups x 16 col-sets. Block 256 thr = 4 waves.
// lanes <-> 64 rows (h from LDS, conflict-free); cols wave-uniform via
// readfirstlane -> W reads compile to s_load (scalar pipe). 4 cols/wave.
__global__ void __launch_bounds__(256) glr_gemm(const float* __restrict__ hmat,
                                                const float* __restrict__ Wl,
                                                const float* __restrict__ Wr,
                                                float* __restrict__ glh,
                                                float* __restrict__ grh) {
    __shared__ float hp[64 * HPSTR];  // 66.6 KB
    const int tid = threadIdx.x;
    const int rg = blockIdx.x & 15;   // row-group of 64 rows
    const int cs = blockIdx.x >> 4;   // col-set of 16 cols

    // Stage 64 rows x 256 floats of h, fully coalesced (float4 flat).
    const float4* __restrict__ hsrc = (const float4*)hmat + rg * (64 * 64);
#pragma unroll
    for (int i = 0; i < 16; ++i) {
        const int v = tid + i * 256;          // flat float4 index
        const int row = v >> 6, kq = v & 63;
        const float4 x = hsrc[v];
        *(float4*)(hp + row * HPSTR + kq * 4) = x;
    }
    __syncthreads();

    const int lane = tid & 63;
    const int wu = __builtin_amdgcn_readfirstlane(tid >> 6);  // wave id, provably uniform
    const int c0 = cs * 16 + wu * 4;          // 4 consecutive cols, same W half
    const float* __restrict__ wbase = (c0 < OUT_F) ? (Wl + c0 * IN_F)
                                                   : (Wr + (c0 - OUT_F) * IN_F);
    const float* __restrict__ hrow = hp + lane * HPSTR;

    float a0 = 0.f, a1 = 0.f, a2 = 0.f, a3 = 0.f;
#pragma unroll 4
    for (int kq = 0; kq < 64; ++kq) {
        const float4 hv = *(const float4*)(hrow + kq * 4);
        const float4 w0 = *(const float4*)(wbase + 0 * IN_F + kq * 4);  // s_load
        const float4 w1 = *(const float4*)(wbase + 1 * IN_F + kq * 4);
        const float4 w2 = *(const float4*)(wbase + 2 * IN_F + kq * 4);
        const float4 w3 = *(const float4*)(wbase + 3 * IN_F + kq * 4);
        a0 = fmaf(hv.x, w0.x, fmaf(hv.y, w0.y, fmaf(hv.z, w0.z, fmaf(hv.w, w0.w, a0))));
        a1 = fmaf(hv.x, w1.x, fmaf(hv.y, w1.y, fmaf(hv.z, w1.z, fmaf(hv.w, w1.w, a1))));
        a2 = fmaf(hv.x, w2.x, fmaf(hv.y, w2.y, fmaf(hv.z, w2.z, fmaf(hv.w, w2.w, a2))));
        a3 = fmaf(hv.x, w3.x, fmaf(hv.y, w3.y, fmaf(hv.z, w3.z, fmaf(hv.w, w3.w, a3))));
    }

    const int row = rg * 64 + lane;
    const int cb = c0 & (OUT_F - 1);
    const int hh = cb >> 5;
    const int f  = cb & 31;                   // multiple of 4 -> 16B-aligned store
    float* __restrict__ dst = (c0 < OUT_F) ? glh : grh;
    float4 r; r.x = a0; r.y = a1; r.z = a2; r.w = a3;
    *(float4*)(dst + (hh * NN + row) * NHF + f) = r;
}

// K2: one block per (i-tile of 8, head); 512 thr.
// Phase A fused: e = 0.6*alpha_j + 0.4*sum_f w_f*|gl_jf + gr_if|  (beta_i term
// cancels in softmax and is dropped; e is O(1) so no max pass is needed),
// p = adj ? exp(e) : 0 written to LDS, row-sum accumulated on the fly.
// Phase C: o[ii,f] = sum_j p*g_r. Restructured this round: thread <-> (f-PAIR,
// j-slice of 32). Each p_buf b128 read now feeds 8 FMAs (2 f-cols) instead of 4,
// halving the LDS-pipe traffic that dominated gat_main (128 -> 64 b128/thread).
// Per-slice j-rotation (8*(js&3)) keeps the 4 distinct slice addresses per wave
// on disjoint bank quads (without it: 4-way b128 conflict).
__global__ void __launch_bounds__(512) gat_main(const float* __restrict__ glh,
                                                const float* __restrict__ grh,
                                                const int* __restrict__ adj,
                                                const float* __restrict__ attn_w,
                                                float* __restrict__ out) {
    const int hh  = blockIdx.y;
    const int i0  = blockIdx.x * 8;
    const int tid = threadIdx.x;

    __shared__ float p_buf[8][1028];   // stride%32==4 -> optimal b128 banking
    __shared__ float part[8][32][34];  // [ii][j-slice][f]; pad 34: b64 writes <=4-way,
                                       // reduce reads conflict-free
    __shared__ float red[8][8];
    __shared__ float l_sh[8];

    float lpart[8];
#pragma unroll
    for (int ii = 0; ii < 8; ++ii) lpart[ii] = 0.f;

    // ---- Phase A (e + exp + row-sum fused) ----
    for (int c = 0; c < 2; ++c) {
        const int j = (c << 9) + tid;
        const float* __restrict__ gp = glh + (hh * NN + j) * NHF;
        float gl[NHF];
#pragma unroll
        for (int f4 = 0; f4 < 8; ++f4) {
            const float4 v = *(const float4*)(gp + (f4 << 2));
            gl[4 * f4 + 0] = v.x; gl[4 * f4 + 1] = v.y;
            gl[4 * f4 + 2] = v.z; gl[4 * f4 + 3] = v.w;
        }
        float alpha = 0.f;
#pragma unroll
        for (int f = 0; f < NHF; ++f) alpha = fmaf(gl[f], attn_w[f], alpha);
        int adjv[8];
#pragma unroll
        for (int ii = 0; ii < 8; ++ii) adjv[ii] = adj[(i0 + ii) * NN + j];
#pragma unroll
        for (int ii = 0; ii < 8; ++ii) {
            const float* __restrict__ grp = grh + (hh * NN + i0 + ii) * NHF;  // uniform -> s_load
            float S0 = 0.f, S1 = 0.f;
#pragma unroll
            for (int f = 0; f < NHF; f += 2) {
                const float s0 = gl[f]     + grp[f];
                const float s1 = gl[f + 1] + grp[f + 1];
                S0 = fmaf(fabsf(s0), attn_w[f],     S0);
                S1 = fmaf(fabsf(s1), attn_w[f + 1], S1);
            }
            const float e = fmaf(0.4f, S0 + S1, 0.6f * alpha);
            const float p = adjv[ii] ? __expf(e) : 0.f;
            p_buf[ii][j] = p;
            lpart[ii] += p;
        }
    }

    // ---- row-sum reduction ----
    const int lane = tid & 63, wv = tid >> 6;
#pragma unroll
    for (int ii = 0; ii < 8; ++ii) {
        float v = lpart[ii];
#pragma unroll
        for (int d = 32; d > 0; d >>= 1) v += __shfl_xor(v, d);
        if (lane == 0) red[ii][wv] = v;
    }
    __syncthreads();
    if (tid < 8) {
        float l = red[tid][0];
#pragma unroll
        for (int w = 1; w < 8; ++w) l += red[tid][w];
        l_sh[tid] = l;
    }
    __syncthreads();

    // ---- Phase C ----
    const int fs = tid & 15;                  // f-pair slot: f = 2*fs, 2*fs+1
    const int js = tid >> 4;                  // 32 j-slices of 32
    const int rot = (js & 3) << 3;            // per-slice rotation -> disjoint banks
    const float* __restrict__ gp = grh + hh * NN * NHF + (fs << 1);
    float o0[8], o1[8];
#pragma unroll
    for (int ii = 0; ii < 8; ++ii) { o0[ii] = 0.f; o1[ii] = 0.f; }
    const int jb = js << 5;
    for (int jj = 0; jj < 32; jj += 4) {
        const int j = jb + ((jj + rot) & 31);
        const float2 g0 = *(const float2*)(gp + (j + 0) * NHF);
        const float2 g1 = *(const float2*)(gp + (j + 1) * NHF);
        const float2 g2 = *(const float2*)(gp + (j + 2) * NHF);
        const float2 g3 = *(const float2*)(gp + (j + 3) * NHF);
#pragma unroll
        for (int ii = 0; ii < 8; ++ii) {
            const float4 p4 = *(const float4*)&p_buf[ii][j];
            o0[ii] = fmaf(p4.x, g0.x, fmaf(p4.y, g1.x, fmaf(p4.z, g2.x, fmaf(p4.w, g3.x, o0[ii]))));
            o1[ii] = fmaf(p4.x, g0.y, fmaf(p4.y, g1.y, fmaf(p4.z, g2.y, fmaf(p4.w, g3.y, o1[ii]))));
        }
    }
#pragma unroll
    for (int ii = 0; ii < 8; ++ii) {
        float2 t; t.x = o0[ii]; t.y = o1[ii];
        *(float2*)&part[ii][js][fs << 1] = t;
    }
    __syncthreads();

    if (tid < 256) {
        const int ii = tid >> 5, ff = tid & 31;
        float s0 = 0.f, s1 = 0.f, s2 = 0.f, s3 = 0.f;
#pragma unroll
        for (int k = 0; k < 32; k += 4) {
            s0 += part[ii][k + 0][ff];
            s1 += part[ii][k + 1][ff];
            s2 += part[ii][k + 2][ff];
            s3 += part[ii][k + 3][ff];
        }
        float s = (s0 + s1) + (s2 + s3);
        s /= l_sh[ii];
        const float r = (s > 0.f) ? s : (__expf(s) - 1.f);
        out[(i0 + ii) * OUT_F + hh * NHF + ff] = r;
    }
}

extern "C" void kernel_launch(void* const* d_in, const int* in_sizes, int n_in,
                              void* d_out, int out_size, void* d_ws, size_t ws_size,
                              hipStream_t stream) {
    const float* hmat = (const float*)d_in[0];
    const int*   adj  = (const int*)d_in[1];
    const float* Wl   = (const float*)d_in[2];
    const float* Wr   = (const float*)d_in[3];
    const float* aw   = (const float*)d_in[4];
    float* o          = (float*)d_out;

    float* glh = (float*)d_ws;                 // [4][1024][32]
    float* grh = glh + NHEADS * NN * NHF;      // [4][1024][32]

    glr_gemm<<<dim3(256), dim3(256), 0, stream>>>(hmat, Wl, Wr, glh, grh);
    gat_main<<<dim3(NN / 8, NHEADS), dim3(512), 0, stream>>>(glh, grh, adj, aw, o);
}

// Round 4
// 106.863 us; speedup vs baseline: 1.0428x; 1.0428x over previous
//
#include <hip/hip_runtime.h>
#include <math.h>

#define NN 1024
#define IN_F 256
#define OUT_F 128
#define NHEADS 4
#define NHF 32
#define ITILE 4
#define HPSTR 260  // LDS h-tile row stride in dwords: 256+4. 260%32==4 -> every
                   // ds_read_b128 across 64 lanes lands exactly 8 dwords/bank (the
                   // b128 floor) -> no bank-conflict penalty.

// K1: g_l = h @ Wl^T, g_r = h @ Wr^T -> [head][row][f] fp32.
// Grid 256 = 16 row-groups x 16 col-sets. Block 256 thr = 4 waves.
// lanes <-> 64 rows (h from LDS, conflict-free); cols wave-uniform via
// readfirstlane -> W reads compile to s_load (scalar pipe). 4 cols/wave.
__global__ void __launch_bounds__(256) glr_gemm(const float* __restrict__ hmat,
                                                const float* __restrict__ Wl,
                                                const float* __restrict__ Wr,
                                                float* __restrict__ glh,
                                                float* __restrict__ grh) {
    __shared__ float hp[64 * HPSTR];  // 66.6 KB
    const int tid = threadIdx.x;
    const int rg = blockIdx.x & 15;   // row-group of 64 rows
    const int cs = blockIdx.x >> 4;   // col-set of 16 cols

    // Stage 64 rows x 256 floats of h, fully coalesced (float4 flat).
    const float4* __restrict__ hsrc = (const float4*)hmat + rg * (64 * 64);
#pragma unroll
    for (int i = 0; i < 16; ++i) {
        const int v = tid + i * 256;          // flat float4 index
        const int row = v >> 6, kq = v & 63;
        const float4 x = hsrc[v];
        *(float4*)(hp + row * HPSTR + kq * 4) = x;
    }
    __syncthreads();

    const int lane = tid & 63;
    const int wu = __builtin_amdgcn_readfirstlane(tid >> 6);  // wave id, provably uniform
    const int c0 = cs * 16 + wu * 4;          // 4 consecutive cols, same W half
    const float* __restrict__ wbase = (c0 < OUT_F) ? (Wl + c0 * IN_F)
                                                   : (Wr + (c0 - OUT_F) * IN_F);
    const float* __restrict__ hrow = hp + lane * HPSTR;

    float a0 = 0.f, a1 = 0.f, a2 = 0.f, a3 = 0.f;
#pragma unroll 4
    for (int kq = 0; kq < 64; ++kq) {
        const float4 hv = *(const float4*)(hrow + kq * 4);
        const float4 w0 = *(const float4*)(wbase + 0 * IN_F + kq * 4);  // s_load
        const float4 w1 = *(const float4*)(wbase + 1 * IN_F + kq * 4);
        const float4 w2 = *(const float4*)(wbase + 2 * IN_F + kq * 4);
        const float4 w3 = *(const float4*)(wbase + 3 * IN_F + kq * 4);
        a0 = fmaf(hv.x, w0.x, fmaf(hv.y, w0.y, fmaf(hv.z, w0.z, fmaf(hv.w, w0.w, a0))));
        a1 = fmaf(hv.x, w1.x, fmaf(hv.y, w1.y, fmaf(hv.z, w1.z, fmaf(hv.w, w1.w, a1))));
        a2 = fmaf(hv.x, w2.x, fmaf(hv.y, w2.y, fmaf(hv.z, w2.z, fmaf(hv.w, w2.w, a2))));
        a3 = fmaf(hv.x, w3.x, fmaf(hv.y, w3.y, fmaf(hv.z, w3.z, fmaf(hv.w, w3.w, a3))));
    }

    const int row = rg * 64 + lane;
    const int cb = c0 & (OUT_F - 1);
    const int hh = cb >> 5;
    const int f  = cb & 31;                   // multiple of 4 -> 16B-aligned store
    float* __restrict__ dst = (c0 < OUT_F) ? glh : grh;
    float4 r; r.x = a0; r.y = a1; r.z = a2; r.w = a3;
    *(float4*)(dst + (hh * NN + row) * NHF + f) = r;
}

// K2: one block per (i-tile of 4, head); 512 thr = 8 waves.
// Round-2 restructure for OCCUPANCY (was 68 KB LDS -> 2 blocks/CU, Occ 19%,
// VALUBusy 38%, both pipes idle -> latency-bound): ITILE 8->4 halves p_buf,
// Phase-C partials reduced across the 4 js-groups of each wave via shfl_xor
// (kills the 35 KB part buffer; LDS ~21 KB). Grid 1024 blocks -> 4 blocks/CU,
// 32 waves/CU. __launch_bounds__(512,8) pins VGPR<=64 for 8 waves/SIMD.
__global__ void __launch_bounds__(512, 8) gat_main(const float* __restrict__ glh,
                                                   const float* __restrict__ grh,
                                                   const int* __restrict__ adj,
                                                   const float* __restrict__ attn_w,
                                                   float* __restrict__ out) {
    const int hh  = blockIdx.y;
    const int i0  = blockIdx.x * ITILE;
    const int tid = threadIdx.x;

    __shared__ float p_buf[ITILE][1028];   // stride%32==4 -> optimal b128 banking
    __shared__ float part[ITILE][8][34];   // [ii][wave][f], pad 34
    __shared__ float red[ITILE][8];
    __shared__ float l_sh[ITILE];

    float lpart[ITILE];
#pragma unroll
    for (int ii = 0; ii < ITILE; ++ii) lpart[ii] = 0.f;

    // ---- Phase A (e + exp + row-sum fused) ----
#pragma unroll 1
    for (int c = 0; c < 2; ++c) {
        const int j = (c << 9) + tid;
        const float* __restrict__ gp = glh + (hh * NN + j) * NHF;
        float gl[NHF];
#pragma unroll
        for (int f4 = 0; f4 < 8; ++f4) {
            const float4 v = *(const float4*)(gp + (f4 << 2));
            gl[4 * f4 + 0] = v.x; gl[4 * f4 + 1] = v.y;
            gl[4 * f4 + 2] = v.z; gl[4 * f4 + 3] = v.w;
        }
        // alpha = sum_f w_f * gl_f, 4 independent chains (latency)
        float al0 = 0.f, al1 = 0.f, al2 = 0.f, al3 = 0.f;
#pragma unroll
        for (int f = 0; f < NHF; f += 4) {
            al0 = fmaf(gl[f + 0], attn_w[f + 0], al0);
            al1 = fmaf(gl[f + 1], attn_w[f + 1], al1);
            al2 = fmaf(gl[f + 2], attn_w[f + 2], al2);
            al3 = fmaf(gl[f + 3], attn_w[f + 3], al3);
        }
        const float alpha = (al0 + al1) + (al2 + al3);
        int adjv[ITILE];
#pragma unroll
        for (int ii = 0; ii < ITILE; ++ii) adjv[ii] = adj[(i0 + ii) * NN + j];
#pragma unroll
        for (int ii = 0; ii < ITILE; ++ii) {
            const float* __restrict__ grp = grh + (hh * NN + i0 + ii) * NHF;  // uniform -> s_load
            float S0 = 0.f, S1 = 0.f, S2 = 0.f, S3 = 0.f;
#pragma unroll
            for (int f = 0; f < NHF; f += 4) {
                const float s0 = gl[f + 0] + grp[f + 0];
                const float s1 = gl[f + 1] + grp[f + 1];
                const float s2 = gl[f + 2] + grp[f + 2];
                const float s3 = gl[f + 3] + grp[f + 3];
                S0 = fmaf(fabsf(s0), attn_w[f + 0], S0);
                S1 = fmaf(fabsf(s1), attn_w[f + 1], S1);
                S2 = fmaf(fabsf(s2), attn_w[f + 2], S2);
                S3 = fmaf(fabsf(s3), attn_w[f + 3], S3);
            }
            const float e = fmaf(0.4f, (S0 + S1) + (S2 + S3), 0.6f * alpha);
            const float p = adjv[ii] ? __expf(e) : 0.f;
            p_buf[ii][j] = p;
            lpart[ii] += p;
        }
    }

    // ---- row-sum reduction ----
    const int lane = tid & 63, wv = tid >> 6;
#pragma unroll
    for (int ii = 0; ii < ITILE; ++ii) {
        float v = lpart[ii];
#pragma unroll
        for (int d = 32; d > 0; d >>= 1) v += __shfl_xor(v, d);
        if (lane == 0) red[ii][wv] = v;
    }
    __syncthreads();
    if (tid < ITILE) {
        float l = red[tid][0];
#pragma unroll
        for (int w = 1; w < 8; ++w) l += red[tid][w];
        l_sh[tid] = l;
    }
    __syncthreads();

    // ---- Phase C: o[ii,f] = sum_j p * g_r ----
    // thread <-> (f-pair fs, j-slice js of 32). Each p_buf b128 feeds 8 FMAs.
    // Per-slice j-rotation (8*(js&3)) keeps the 4 slice addresses per wave on
    // disjoint bank quads. After the j-loop, shfl_xor(16/32) folds the 4
    // js-groups of the wave -> one partial per (wave, f) in 4.3 KB of LDS.
    const int fs = tid & 15;                  // f-pair slot: f = 2*fs, 2*fs+1
    const int js = tid >> 4;                  // 32 j-slices of 32
    const int rot = (js & 3) << 3;            // per-slice rotation -> disjoint banks
    const float* __restrict__ gp = grh + hh * NN * NHF + (fs << 1);
    float o0[ITILE], o1[ITILE];
#pragma unroll
    for (int ii = 0; ii < ITILE; ++ii) { o0[ii] = 0.f; o1[ii] = 0.f; }
    const int jb = js << 5;
    for (int jj = 0; jj < 32; jj += 4) {
        const int j = jb + ((jj + rot) & 31);
        const float2 g0 = *(const float2*)(gp + (j + 0) * NHF);
        const float2 g1 = *(const float2*)(gp + (j + 1) * NHF);
        const float2 g2 = *(const float2*)(gp + (j + 2) * NHF);
        const float2 g3 = *(const float2*)(gp + (j + 3) * NHF);
#pragma unroll
        for (int ii = 0; ii < ITILE; ++ii) {
            const float4 p4 = *(const float4*)&p_buf[ii][j];
            o0[ii] = fmaf(p4.x, g0.x, fmaf(p4.y, g1.x, fmaf(p4.z, g2.x, fmaf(p4.w, g3.x, o0[ii]))));
            o1[ii] = fmaf(p4.x, g0.y, fmaf(p4.y, g1.y, fmaf(p4.z, g2.y, fmaf(p4.w, g3.y, o1[ii]))));
        }
    }
    // fold the 4 js-groups within the wave (lane bits 4,5)
#pragma unroll
    for (int ii = 0; ii < ITILE; ++ii) {
        o0[ii] += __shfl_xor(o0[ii], 16);
        o0[ii] += __shfl_xor(o0[ii], 32);
        o1[ii] += __shfl_xor(o1[ii], 16);
        o1[ii] += __shfl_xor(o1[ii], 32);
    }
    if (lane < 16) {                          // fs == lane
#pragma unroll
        for (int ii = 0; ii < ITILE; ++ii) {
            float2 t; t.x = o0[ii]; t.y = o1[ii];
            *(float2*)&part[ii][wv][fs << 1] = t;
        }
    }
    __syncthreads();

    if (tid < 32 * ITILE) {
        const int ii = tid >> 5, ff = tid & 31;
        float s0 = 0.f, s1 = 0.f;
#pragma unroll
        for (int w = 0; w < 8; w += 2) {
            s0 += part[ii][w + 0][ff];
            s1 += part[ii][w + 1][ff];
        }
        float s = (s0 + s1) / l_sh[ii];
        const float r = (s > 0.f) ? s : (__expf(s) - 1.f);
        out[(i0 + ii) * OUT_F + hh * NHF + ff] = r;
    }
}

extern "C" void kernel_launch(void* const* d_in, const int* in_sizes, int n_in,
                              void* d_out, int out_size, void* d_ws, size_t ws_size,
                              hipStream_t stream) {
    const float* hmat = (const float*)d_in[0];
    const int*   adj  = (const int*)d_in[1];
    const float* Wl   = (const float*)d_in[2];
    const float* Wr   = (const float*)d_in[3];
    const float* aw   = (const float*)d_in[4];
    float* o          = (float*)d_out;

    float* glh = (float*)d_ws;                 // [4][1024][32]
    float* grh = glh + NHEADS * NN * NHF;      // [4][1024][32]

    glr_gemm<<<dim3(256), dim3(256), 0, stream>>>(hmat, Wl, Wr, glh, grh);
    gat_main<<<dim3(NN / ITILE, NHEADS), dim3(512), 0, stream>>>(glh, grh, adj, aw, o);
}

// Round 5
// 101.115 us; speedup vs baseline: 1.1020x; 1.0568x over previous
//
#include <hip/hip_runtime.h>
#include <math.h>

#define NN 1024
#define IN_F 256
#define OUT_F 128
#define NHEADS 4
#define NHF 32
#define ITILE 4
#define HPSTR 260  // h-tile row stride in dwords; (row,kc) read pattern lands on the
                   // conflict-free b128 floor (8 distinct addrs per bank-quad).

// K1 v5: g_l = h @ Wl^T, g_r = h @ Wr^T -> [head][row][f] fp32.
// R4 postmortem: old design = 1 block/CU, 4 waves/CU, s_load-latency-serial k-loop
// -> ~25us for a 134 MFLOP GEMM. v5: 16-row tiles (16.6 KB LDS), grid 1024 =
// 64 rowgroups x 16 colsets -> 4 blocks/CU, 16 waves/CU. Lanes = 16 rows x 4
// k-chunks of 64; W read as broadcast VMEM float4 (L1-hot 16KB colset, no scalar
// serialization); k-chunks folded with 2 shfl_xor.
__global__ void __launch_bounds__(256, 4) glr_gemm(const float* __restrict__ hmat,
                                                   const float* __restrict__ Wl,
                                                   const float* __restrict__ Wr,
                                                   float* __restrict__ glh,
                                                   float* __restrict__ grh) {
    __shared__ float hp[16 * HPSTR];  // 16.6 KB
    const int tid = threadIdx.x;
    const int rg = blockIdx.x & 63;   // 64 row-groups of 16 rows
    const int cs = blockIdx.x >> 6;   // 16 col-sets of 16 cols

    // Stage 16 rows x 256 floats, coalesced.
    const float4* __restrict__ hsrc = (const float4*)hmat + rg * (16 * 64);
#pragma unroll
    for (int i = 0; i < 4; ++i) {
        const int v = tid + i * 256;
        const int row = v >> 6, kq = v & 63;
        *(float4*)(hp + row * HPSTR + kq * 4) = hsrc[v];
    }
    __syncthreads();

    const int lane = tid & 63;
    const int row  = lane & 15;       // 16 rows
    const int kc   = lane >> 4;       // 4 k-chunks of 64
    const int wu   = __builtin_amdgcn_readfirstlane(tid >> 6);
    const int c0   = cs * 16 + wu * 4;
    const float* __restrict__ wb = (c0 < OUT_F) ? (Wl + c0 * IN_F)
                                                : (Wr + (c0 - OUT_F) * IN_F);
    const float* __restrict__ hrow = hp + row * HPSTR + kc * 64;
    const float* __restrict__ wrow = wb + kc * 64;

    float a0 = 0.f, a1 = 0.f, a2 = 0.f, a3 = 0.f;
#pragma unroll 4
    for (int i = 0; i < 16; ++i) {
        const float4 hv = *(const float4*)(hrow + i * 4);
        const float4 w0 = *(const float4*)(wrow + 0 * IN_F + i * 4);  // broadcast VMEM
        const float4 w1 = *(const float4*)(wrow + 1 * IN_F + i * 4);
        const float4 w2 = *(const float4*)(wrow + 2 * IN_F + i * 4);
        const float4 w3 = *(const float4*)(wrow + 3 * IN_F + i * 4);
        a0 = fmaf(hv.x, w0.x, fmaf(hv.y, w0.y, fmaf(hv.z, w0.z, fmaf(hv.w, w0.w, a0))));
        a1 = fmaf(hv.x, w1.x, fmaf(hv.y, w1.y, fmaf(hv.z, w1.z, fmaf(hv.w, w1.w, a1))));
        a2 = fmaf(hv.x, w2.x, fmaf(hv.y, w2.y, fmaf(hv.z, w2.z, fmaf(hv.w, w2.w, a2))));
        a3 = fmaf(hv.x, w3.x, fmaf(hv.y, w3.y, fmaf(hv.z, w3.z, fmaf(hv.w, w3.w, a3))));
    }
    // fold the 4 k-chunks (lane bits 4,5)
    a0 += __shfl_xor(a0, 16); a0 += __shfl_xor(a0, 32);
    a1 += __shfl_xor(a1, 16); a1 += __shfl_xor(a1, 32);
    a2 += __shfl_xor(a2, 16); a2 += __shfl_xor(a2, 32);
    a3 += __shfl_xor(a3, 16); a3 += __shfl_xor(a3, 32);

    if (kc == 0) {
        const int cb = c0 & (OUT_F - 1);
        const int hh = cb >> 5;
        const int f  = cb & 31;               // multiple of 4 -> aligned float4 store
        float* __restrict__ dst = (c0 < OUT_F) ? glh : grh;
        float4 r; r.x = a0; r.y = a1; r.z = a2; r.w = a3;
        *(float4*)(dst + (hh * NN + rg * 16 + row) * NHF + f) = r;
    }
}

// K2 v5: one block per (i-tile of 4, head); 512 thr = 8 waves; 4 blocks/CU.
// Phase A: sequential f-half loop keeps only g[16] live (R4's gl[32] + 64-VGPR
// cap spilled to scratch: VGPR_Count=32, WRITE_SIZE 14.8MB). ~50 live VGPRs now
// fits launch_bounds(512,8) without spill -> 32 waves/CU AND no scratch.
// Phase C: reverted to the R0 shape (f <-> 32 lanes, 16 j-slices of 64,
// sequential j) — the R0->R2 A/B showed the f-pair+rotation variant cost ~8us.
__global__ void __launch_bounds__(512, 8) gat_main(const float* __restrict__ glh,
                                                   const float* __restrict__ grh,
                                                   const int* __restrict__ adj,
                                                   const float* __restrict__ attn_w,
                                                   float* __restrict__ out) {
    const int hh  = blockIdx.y;
    const int i0  = blockIdx.x * ITILE;
    const int tid = threadIdx.x;

    __shared__ float p_buf[ITILE][1028];   // stride%32==4 -> optimal b128 banking
    __shared__ float part[ITILE][16][NHF]; // [ii][j-slice][f]
    __shared__ float red[ITILE][8];
    __shared__ float l_sh[ITILE];

    float lpart[ITILE];
#pragma unroll
    for (int ii = 0; ii < ITILE; ++ii) lpart[ii] = 0.f;

    // ---- Phase A (e + exp + row-sum fused) ----
#pragma unroll 1
    for (int c = 0; c < 2; ++c) {
        const int j = (c << 9) + tid;
        const float* __restrict__ gp = glh + (hh * NN + j) * NHF;
        int adjv[ITILE];
#pragma unroll
        for (int ii = 0; ii < ITILE; ++ii) adjv[ii] = adj[(i0 + ii) * NN + j];

        float S[ITILE];
#pragma unroll
        for (int ii = 0; ii < ITILE; ++ii) S[ii] = 0.f;
        float alpha = 0.f;

#pragma unroll
        for (int fh = 0; fh < 2; ++fh) {       // f-half loop: only 16 gl live
            const int fb = fh << 4;
            float g[16];
#pragma unroll
            for (int f4 = 0; f4 < 4; ++f4) {
                const float4 v = *(const float4*)(gp + fb + (f4 << 2));
                g[4 * f4 + 0] = v.x; g[4 * f4 + 1] = v.y;
                g[4 * f4 + 2] = v.z; g[4 * f4 + 3] = v.w;
            }
#pragma unroll
            for (int k = 0; k < 16; ++k) alpha = fmaf(g[k], attn_w[fb + k], alpha);
#pragma unroll
            for (int ii = 0; ii < ITILE; ++ii) {
                const float* __restrict__ grp = grh + (hh * NN + i0 + ii) * NHF + fb;  // uniform -> s_load
                float s = S[ii];
#pragma unroll
                for (int k = 0; k < 16; ++k)
                    s = fmaf(fabsf(g[k] + grp[k]), attn_w[fb + k], s);
                S[ii] = s;
            }
        }
#pragma unroll
        for (int ii = 0; ii < ITILE; ++ii) {
            const float e = fmaf(0.4f, S[ii], 0.6f * alpha);
            const float p = adjv[ii] ? __expf(e) : 0.f;
            p_buf[ii][j] = p;
            lpart[ii] += p;
        }
    }

    // ---- row-sum reduction ----
    const int lane = tid & 63, wv = tid >> 6;
#pragma unroll
    for (int ii = 0; ii < ITILE; ++ii) {
        float v = lpart[ii];
#pragma unroll
        for (int d = 32; d > 0; d >>= 1) v += __shfl_xor(v, d);
        if (lane == 0) red[ii][wv] = v;
    }
    __syncthreads();
    if (tid < ITILE) {
        float l = red[tid][0];
#pragma unroll
        for (int w = 1; w < 8; ++w) l += red[tid][w];
        l_sh[tid] = l;
    }
    __syncthreads();

    // ---- Phase C (R0 shape): o[ii,f] = sum_j p * g_r ----
    // thread <-> (f, j-slice of 64); p_buf b128 reads are 32-lane broadcasts.
    const int f  = tid & 31;
    const int js = tid >> 5;                  // 16 j-slices of 64
    const float* __restrict__ gp = grh + hh * NN * NHF + f;
    float o[ITILE];
#pragma unroll
    for (int ii = 0; ii < ITILE; ++ii) o[ii] = 0.f;
    const int jb = js << 6;
#pragma unroll 4
    for (int jj = 0; jj < 64; jj += 4) {
        const int j = jb + jj;
        const float g0 = gp[(j + 0) * NHF];
        const float g1 = gp[(j + 1) * NHF];
        const float g2 = gp[(j + 2) * NHF];
        const float g3 = gp[(j + 3) * NHF];
#pragma unroll
        for (int ii = 0; ii < ITILE; ++ii) {
            const float4 p4 = *(const float4*)&p_buf[ii][j];
            o[ii] = fmaf(p4.x, g0, fmaf(p4.y, g1, fmaf(p4.z, g2, fmaf(p4.w, g3, o[ii]))));
        }
    }
#pragma unroll
    for (int ii = 0; ii < ITILE; ++ii) part[ii][js][f] = o[ii];
    __syncthreads();

    if (tid < 32 * ITILE) {
        const int ii = tid >> 5, ff = tid & 31;
        float s0 = 0.f, s1 = 0.f, s2 = 0.f, s3 = 0.f;
#pragma unroll
        for (int k = 0; k < 16; k += 4) {
            s0 += part[ii][k + 0][ff];
            s1 += part[ii][k + 1][ff];
            s2 += part[ii][k + 2][ff];
            s3 += part[ii][k + 3][ff];
        }
        float s = ((s0 + s1) + (s2 + s3)) / l_sh[ii];
        const float r = (s > 0.f) ? s : (__expf(s) - 1.f);
        out[(i0 + ii) * OUT_F + hh * NHF + ff] = r;
    }
}

extern "C" void kernel_launch(void* const* d_in, const int* in_sizes, int n_in,
                              void* d_out, int out_size, void* d_ws, size_t ws_size,
                              hipStream_t stream) {
    const float* hmat = (const float*)d_in[0];
    const int*   adj  = (const int*)d_in[1];
    const float* Wl   = (const float*)d_in[2];
    const float* Wr   = (const float*)d_in[3];
    const float* aw   = (const float*)d_in[4];
    float* o          = (float*)d_out;

    float* glh = (float*)d_ws;                 // [4][1024][32]
    float* grh = glh + NHEADS * NN * NHF;      // [4][1024][32]

    glr_gemm<<<dim3(1024), dim3(256), 0, stream>>>(hmat, Wl, Wr, glh, grh);
    gat_main<<<dim3(NN / ITILE, NHEADS), dim3(512), 0, stream>>>(glh, grh, adj, aw, o);
}

// Round 9
// 99.883 us; speedup vs baseline: 1.1156x; 1.0123x over previous
//
#include <hip/hip_runtime.h>
#include <math.h>

#define NN 1024
#define IN_F 256
#define OUT_F 128
#define NHEADS 4
#define NHF 32
#define ITILE 4
#define HPSTR 260  // h-tile row stride in dwords. Row term gives banks row*4%32,
                   // chunk term is 0 mod 32 -> every ds_read_b128 across 64 lanes
                   // lands exactly 8 dwords/bank = the b128 floor (conflict-free).

typedef float vf2 __attribute__((ext_vector_type(2)));  // -> v_pk_*_f32 on gfx950

// K1 v6: g_l = h @ Wl^T, g_r = h @ Wr^T -> [head][row][f] fp32.
// 8-row tiles (8.3 KB LDS), grid 2048 = 128 rowgroups x 16 colsets -> 8 blocks/CU,
// 32 waves/CU. Lanes = 8 rows x 8 k-chunks of 32; W as broadcast VMEM float4;
// dot products in packed fp32 (v_pk_fma_f32, halves VALU issue); k-chunks folded
// with 3 shfl_xor.
__global__ void __launch_bounds__(256, 8) glr_gemm(const float* __restrict__ hmat,
                                                   const float* __restrict__ Wl,
                                                   const float* __restrict__ Wr,
                                                   float* __restrict__ glh,
                                                   float* __restrict__ grh) {
    __shared__ float hp[8 * HPSTR];  // 8.3 KB
    const int tid = threadIdx.x;
    const int rg = blockIdx.x & 127;  // 128 row-groups of 8 rows
    const int cs = blockIdx.x >> 7;   // 16 col-sets of 16 cols

    // Stage 8 rows x 256 floats, coalesced.
    const float4* __restrict__ hsrc = (const float4*)hmat + rg * (8 * 64);
#pragma unroll
    for (int i = 0; i < 2; ++i) {
        const int v = tid + i * 256;
        const int row = v >> 6, kq = v & 63;
        *(float4*)(hp + row * HPSTR + kq * 4) = hsrc[v];
    }
    __syncthreads();

    const int lane = tid & 63;
    const int row  = lane & 7;        // 8 rows
    const int kc   = lane >> 3;       // 8 k-chunks of 32 floats
    const int wu   = __builtin_amdgcn_readfirstlane(tid >> 6);
    const int c0   = cs * 16 + wu * 4;
    const float* __restrict__ wb = (c0 < OUT_F) ? (Wl + c0 * IN_F)
                                                : (Wr + (c0 - OUT_F) * IN_F);
    const float* __restrict__ hrow = hp + row * HPSTR + kc * 32;
    const float* __restrict__ wrow = wb + kc * 32;

    vf2 a0 = {0.f, 0.f}, a1 = {0.f, 0.f}, a2 = {0.f, 0.f}, a3 = {0.f, 0.f};
#pragma unroll 2
    for (int i = 0; i < 8; ++i) {
        const float4 hv = *(const float4*)(hrow + i * 4);
        const vf2 hA = {hv.x, hv.y};
        const vf2 hB = {hv.z, hv.w};
        const float4 w0 = *(const float4*)(wrow + 0 * IN_F + i * 4);
        const float4 w1 = *(const float4*)(wrow + 1 * IN_F + i * 4);
        const float4 w2 = *(const float4*)(wrow + 2 * IN_F + i * 4);
        const float4 w3 = *(const float4*)(wrow + 3 * IN_F + i * 4);
        a0 = hA * (vf2){w0.x, w0.y} + a0;  a0 = hB * (vf2){w0.z, w0.w} + a0;
        a1 = hA * (vf2){w1.x, w1.y} + a1;  a1 = hB * (vf2){w1.z, w1.w} + a1;
        a2 = hA * (vf2){w2.x, w2.y} + a2;  a2 = hB * (vf2){w2.z, w2.w} + a2;
        a3 = hA * (vf2){w3.x, w3.y} + a3;  a3 = hB * (vf2){w3.z, w3.w} + a3;
    }
    float s0 = a0.x + a0.y, s1 = a1.x + a1.y, s2 = a2.x + a2.y, s3 = a3.x + a3.y;
    // fold the 8 k-chunks (lane bits 3,4,5)
#pragma unroll
    for (int d = 8; d <= 32; d <<= 1) {
        s0 += __shfl_xor(s0, d);
        s1 += __shfl_xor(s1, d);
        s2 += __shfl_xor(s2, d);
        s3 += __shfl_xor(s3, d);
    }

    if (kc == 0) {
        const int cb = c0 & (OUT_F - 1);
        const int hh = cb >> 5;
        const int f  = cb & 31;               // multiple of 4 -> aligned float4 store
        float* __restrict__ dst = (c0 < OUT_F) ? glh : grh;
        float4 r; r.x = s0; r.y = s1; r.z = s2; r.w = s3;
        *(float4*)(dst + (hh * NN + rg * 8 + row) * NHF + f) = r;
    }
}

// K2 v6: one block per (i-tile of 4, head); 512 thr = 8 waves; 4 blocks/CU,
// 32 waves/CU, VGPR<=64 (launch_bounds(512,8)), no scratch (live ~45 regs).
// Phase A: f-half loop (g2[8] live) with PACKED fp32: per 2 f-slots
// pk_add + 2x v_and(abs) + pk_fma (was 6 scalar ops -> 1.5x issue reduction);
// alpha packed too. Phase C: R0 shape (f <-> 32 lanes, 16 j-slices of 64,
// sequential j), packed over jj-pairs: 8 pk_fma/step instead of 16 fma.
__global__ void __launch_bounds__(512, 8) gat_main(const float* __restrict__ glh,
                                                   const float* __restrict__ grh,
                                                   const int* __restrict__ adj,
                                                   const float* __restrict__ attn_w,
                                                   float* __restrict__ out) {
    const int hh  = blockIdx.y;
    const int i0  = blockIdx.x * ITILE;
    const int tid = threadIdx.x;

    __shared__ float p_buf[ITILE][1028];   // stride%32==4 -> optimal b128 banking
    __shared__ float part[ITILE][16][NHF]; // [ii][j-slice][f]
    __shared__ float red[ITILE][8];
    __shared__ float l_sh[ITILE];

    float lpart[ITILE];
#pragma unroll
    for (int ii = 0; ii < ITILE; ++ii) lpart[ii] = 0.f;

    // ---- Phase A (e + exp + row-sum fused) ----
#pragma unroll 1
    for (int c = 0; c < 2; ++c) {
        const int j = (c << 9) + tid;
        const float* __restrict__ gp = glh + (hh * NN + j) * NHF;
        int adjv[ITILE];
#pragma unroll
        for (int ii = 0; ii < ITILE; ++ii) adjv[ii] = adj[(i0 + ii) * NN + j];

        vf2 S2[ITILE];
#pragma unroll
        for (int ii = 0; ii < ITILE; ++ii) S2[ii] = (vf2){0.f, 0.f};
        vf2 alpha2 = {0.f, 0.f};

#pragma unroll
        for (int fh = 0; fh < 2; ++fh) {       // f-half loop: only 16 gl floats live
            const int fb = fh << 4;
            vf2 g2[8];
#pragma unroll
            for (int q = 0; q < 4; ++q) {
                const float4 v = *(const float4*)(gp + fb + (q << 2));
                g2[2 * q + 0] = (vf2){v.x, v.y};
                g2[2 * q + 1] = (vf2){v.z, v.w};
            }
#pragma unroll
            for (int k2 = 0; k2 < 8; ++k2) {
                const vf2 w2 = *(const vf2*)(attn_w + fb + 2 * k2);   // s_load
                alpha2 = g2[k2] * w2 + alpha2;
            }
#pragma unroll
            for (int ii = 0; ii < ITILE; ++ii) {
                const float* __restrict__ grp = grh + (hh * NN + i0 + ii) * NHF + fb;  // uniform -> s_load
                vf2 acc = S2[ii];
#pragma unroll
                for (int k2 = 0; k2 < 8; ++k2) {
                    const vf2 s = g2[k2] + *(const vf2*)(grp + 2 * k2);
                    vf2 a; a.x = fabsf(s.x); a.y = fabsf(s.y);
                    acc = a * (*(const vf2*)(attn_w + fb + 2 * k2)) + acc;
                }
                S2[ii] = acc;
            }
        }
#pragma unroll
        for (int ii = 0; ii < ITILE; ++ii) {
            const float e = fmaf(0.4f, S2[ii].x + S2[ii].y,
                                 0.6f * (alpha2.x + alpha2.y));
            const float p = adjv[ii] ? __expf(e) : 0.f;
            p_buf[ii][j] = p;
            lpart[ii] += p;
        }
    }

    // ---- row-sum reduction ----
    const int lane = tid & 63, wv = tid >> 6;
#pragma unroll
    for (int ii = 0; ii < ITILE; ++ii) {
        float v = lpart[ii];
#pragma unroll
        for (int d = 32; d > 0; d >>= 1) v += __shfl_xor(v, d);
        if (lane == 0) red[ii][wv] = v;
    }
    __syncthreads();
    if (tid < ITILE) {
        float l = red[tid][0];
#pragma unroll
        for (int w = 1; w < 8; ++w) l += red[tid][w];
        l_sh[tid] = l;
    }
    __syncthreads();

    // ---- Phase C: o[ii,f] = sum_j p * g_r (packed over jj-pairs) ----
    const int f  = tid & 31;
    const int js = tid >> 5;                  // 16 j-slices of 64
    const float* __restrict__ gp = grh + hh * NN * NHF + f;
    vf2 o2[ITILE];
#pragma unroll
    for (int ii = 0; ii < ITILE; ++ii) o2[ii] = (vf2){0.f, 0.f};
    const int jb = js << 6;
#pragma unroll 4
    for (int jj = 0; jj < 64; jj += 4) {
        const int j = jb + jj;
        const float g0 = gp[(j + 0) * NHF];
        const float g1 = gp[(j + 1) * NHF];
        const float g2 = gp[(j + 2) * NHF];
        const float g3 = gp[(j + 3) * NHF];
        const vf2 gA = {g0, g1};
        const vf2 gB = {g2, g3};
#pragma unroll
        for (int ii = 0; ii < ITILE; ++ii) {
            const float4 p4 = *(const float4*)&p_buf[ii][j];
            o2[ii] = (vf2){p4.x, p4.y} * gA + o2[ii];
            o2[ii] = (vf2){p4.z, p4.w} * gB + o2[ii];
        }
    }
#pragma unroll
    for (int ii = 0; ii < ITILE; ++ii) part[ii][js][f] = o2[ii].x + o2[ii].y;
    __syncthreads();

    if (tid < 32 * ITILE) {
        const int ii = tid >> 5, ff = tid & 31;
        float s0 = 0.f, s1 = 0.f, s2 = 0.f, s3 = 0.f;
#pragma unroll
        for (int k = 0; k < 16; k += 4) {
            s0 += part[ii][k + 0][ff];
            s1 += part[ii][k + 1][ff];
            s2 += part[ii][k + 2][ff];
            s3 += part[ii][k + 3][ff];
        }
        float s = ((s0 + s1) + (s2 + s3)) / l_sh[ii];
        const float r = (s > 0.f) ? s : (__expf(s) - 1.f);
        out[(i0 + ii) * OUT_F + hh * NHF + ff] = r;
    }
}

extern "C" void kernel_launch(void* const* d_in, const int* in_sizes, int n_in,
                              void* d_out, int out_size, void* d_ws, size_t ws_size,
                              hipStream_t stream) {
    const float* hmat = (const float*)d_in[0];
    const int*   adj  = (const int*)d_in[1];
    const float* Wl   = (const float*)d_in[2];
    const float* Wr   = (const float*)d_in[3];
    const float* aw   = (const float*)d_in[4];
    float* o          = (float*)d_out;

    float* glh = (float*)d_ws;                 // [4][1024][32]
    float* grh = glh + NHEADS * NN * NHF;      // [4][1024][32]

    glr_gemm<<<dim3(2048), dim3(256), 0, stream>>>(hmat, Wl, Wr, glh, grh);
    gat_main<<<dim3(NN / ITILE, NHEADS), dim3(512), 0, stream>>>(glh, grh, adj, aw, o);
}